// Round 3
// baseline (789.487 us; speedup 1.0000x reference)
//
#include <hip/hip_runtime.h>
#include <stdint.h>
#include <math.h>

// Problem constants (fixed by reference setup_inputs)
#define B_SZ   32
#define T_LEN  2048
#define DIN    512
#define DD     512
#define M_TOT  (B_SZ * T_LEN)   // 65536 rows
#define NTHREADS 256
#define WSZ    ((size_t)DD * DD)

typedef unsigned short u16;
typedef __attribute__((ext_vector_type(8))) short short8;
typedef __attribute__((ext_vector_type(4))) float f32x4;

// ---------------------------------------------------------------------------
// fp32 -> bf16 round-to-nearest-even
// ---------------------------------------------------------------------------
__device__ __forceinline__ u16 f2bf(float f) {
  uint32_t u = __float_as_uint(f);
  uint32_t r = (u + 0x7FFFu + ((u >> 16) & 1u)) >> 16;
  return (u16)r;
}

// async global->LDS, 16B per lane; LDS dest = wave-uniform base + lane*16
typedef const void __attribute__((address_space(1)))* as1cp;
typedef void __attribute__((address_space(3)))* as3p;
__device__ __forceinline__ void async16(const void* g, void* l) {
  __builtin_amdgcn_global_load_lds((as1cp)(uintptr_t)g,
                                   (as3p)(uint32_t)(uintptr_t)l, 16, 0, 0);
}

// ---------------------------------------------------------------------------
// Threefry-2x32 (20 rounds), bit-exact vs JAX's threefry2x32 primitive.
// ---------------------------------------------------------------------------
__device__ __forceinline__ uint32_t rotl32(uint32_t x, int n) {
  return (x << n) | (x >> (32 - n));
}

__device__ __forceinline__ void threefry2x32(uint32_t k0, uint32_t k1,
                                             uint32_t x0, uint32_t x1,
                                             uint32_t& o0, uint32_t& o1) {
  const uint32_t ks0 = k0, ks1 = k1, ks2 = k0 ^ k1 ^ 0x1BD11BDAu;
  uint32_t v0 = x0 + ks0, v1 = x1 + ks1;
#define TF_R(r) { v0 += v1; v1 = rotl32(v1, (r)); v1 ^= v0; }
  TF_R(13) TF_R(15) TF_R(26) TF_R(6)
  v0 += ks1; v1 += ks2 + 1u;
  TF_R(17) TF_R(29) TF_R(16) TF_R(24)
  v0 += ks2; v1 += ks0 + 2u;
  TF_R(13) TF_R(15) TF_R(26) TF_R(6)
  v0 += ks0; v1 += ks1 + 3u;
  TF_R(17) TF_R(29) TF_R(16) TF_R(24)
  v0 += ks1; v1 += ks2 + 4u;
  TF_R(13) TF_R(15) TF_R(26) TF_R(6)
  v0 += ks2; v1 += ks0 + 5u;
#undef TF_R
  o0 = v0; o1 = v1;
}

// ---------------------------------------------------------------------------
// Noise under JAX_ENABLE_X64=1 + partitionable threefry (modern default):
//   split (foldlike, dtype-independent): keys[j] = threefry(key, (0, j))
//   bernoulli(key, p, shape): p is a Python float -> float64 in x64 mode ->
//     uniform draws 64-bit bits: bits64[i] = (b1<<32)|b2, counter (0, i);
//     u = f64((bits64 >> 12) | 0x3FF0000000000000) - 1.0
//   Integer reduction of the compare (monotone bitcast):
//     u < 0.25 <=> bits64 < 2^62      <=> b1 < 0x40000000
//     u < 0.75 <=> bits64 < 3*2^62    <=> b1 < 0xC0000000
// ---------------------------------------------------------------------------
__global__ void noise_kernel(float* __restrict__ noise_i, float* __restrict__ noise_s) {
  int i = blockIdx.x * blockDim.x + threadIdx.x;
  if (i >= B_SZ * DIN) return;
  uint32_t k1a, k1b, k2a, k2b;
  threefry2x32(0u, 42u, 0u, 0u, k1a, k1b);
  threefry2x32(0u, 42u, 0u, 1u, k2a, k2b);
  uint32_t b1, b2;
  threefry2x32(k1a, k1b, 0u, (uint32_t)i, b1, b2);
  noise_i[i] = (b1 < 0x40000000u) ? 4.0f : 0.0f;
  threefry2x32(k2a, k2b, 0u, (uint32_t)i, b1, b2);
  noise_s[i] = (b1 < 0xC0000000u) ? (1.0f / 0.75f) : 0.0f;
}

// layer-0 state projections, exact fp32 (t-independent):
// vH0[b,c] = sum_k h0[k]*noise_s[b,k]*recurH_w[0][k,c] + recurH_b[0][c]
// grid 64: block = (b, half). Coalesced W reads; sdv staged in LDS.
__global__ __launch_bounds__(256) void vec0_kernel(
    const float* __restrict__ h0, const float* __restrict__ noise_s,
    const float* __restrict__ rHw, const float* __restrict__ rHb,
    const float* __restrict__ rTw, const float* __restrict__ rTb,
    float* __restrict__ vH0, float* __restrict__ vT0) {
  __shared__ float sdv[DD];
  const int b = blockIdx.x >> 1;
  const int c = (blockIdx.x & 1) * 256 + threadIdx.x;
  for (int k = threadIdx.x; k < DD; k += 256)
    sdv[k] = h0[k] * noise_s[b * DD + k];
  __syncthreads();
  float aH = 0.f, aT = 0.f;
  for (int k = 0; k < DD; ++k) {
    float v = sdv[k];
    aH += v * rHw[(size_t)k * DD + c];
    aT += v * rTw[(size_t)k * DD + c];
  }
  vH0[b * DD + c] = aH + rHb[c];
  vT0[b * DD + c] = aT + rTb[c];
}

// ---------------------------------------------------------------------------
// Transpose+convert all six 512x512 fp32 W[k][n] -> bf16 Wt[n][k].
// grid 384 = 6 matrices x 64 tiles of 64x64.
// Wt order: 0=wH 1=wT 2=r1H 3=r1T 4=r2H 5=r2T
// ---------------------------------------------------------------------------
__global__ __launch_bounds__(256) void wt_all(
    const float* __restrict__ wH, const float* __restrict__ wT,
    const float* __restrict__ rHw, const float* __restrict__ rTw,
    u16* __restrict__ Wt) {
  __shared__ float tile[64][68];
  const int which = blockIdx.x >> 6;
  const float* W;
  switch (which) {
    case 0: W = wH; break;
    case 1: W = wT; break;
    case 2: W = rHw + WSZ; break;
    case 3: W = rTw + WSZ; break;
    case 4: W = rHw + 2 * WSZ; break;
    default: W = rTw + 2 * WSZ; break;
  }
  u16* dst = Wt + (size_t)which * WSZ;
  const int tb = blockIdx.x & 63;
  const int kt = (tb >> 3) * 64;
  const int nt = (tb & 7) * 64;
  const int tid = threadIdx.x;
  {
    int r = tid >> 2;
#pragma unroll
    for (int u = 0; u < 4; ++u) {
      int c = ((tid & 3) + u * 4) * 4;
      float4 v = *(const float4*)(W + (size_t)(kt + r) * DD + nt + c);
      tile[r][c] = v.x; tile[r][c + 1] = v.y; tile[r][c + 2] = v.z; tile[r][c + 3] = v.w;
    }
  }
  __syncthreads();
  {
    int n = tid >> 2, seg = (tid & 3) * 16;
    u16 o[16];
#pragma unroll
    for (int u = 0; u < 16; ++u) o[u] = f2bf(tile[seg + u][n]);
    *(uint4*)(dst + (size_t)(nt + n) * DD + kt + seg) = *(const uint4*)o;
    *(uint4*)(dst + (size_t)(nt + n) * DD + kt + seg + 8) = *(const uint4*)(o + 8);
  }
}

// ---------------------------------------------------------------------------
// Xbf[m][k] = bf16(seq[m][k] * noise_i[b][k]);  one thread per 8 elements.
// ---------------------------------------------------------------------------
__global__ __launch_bounds__(256) void xprep(const float* __restrict__ seq,
                                             const float* __restrict__ noise_i,
                                             u16* __restrict__ Xbf) {
  int idx = blockIdx.x * 256 + threadIdx.x;   // 4,194,304 granules of 8
  int row = idx >> 6;
  int k8 = (idx & 63) * 8;
  int b = row >> 11;
  const float* s = seq + (size_t)row * DIN + k8;
  const float* n = noise_i + b * DIN + k8;
  float4 s0 = *(const float4*)s, s1 = *(const float4*)(s + 4);
  float4 n0 = *(const float4*)n, n1 = *(const float4*)(n + 4);
  u16 o[8];
  o[0] = f2bf(s0.x * n0.x); o[1] = f2bf(s0.y * n0.y);
  o[2] = f2bf(s0.z * n0.z); o[3] = f2bf(s0.w * n0.w);
  o[4] = f2bf(s1.x * n1.x); o[5] = f2bf(s1.y * n1.y);
  o[6] = f2bf(s1.z * n1.z); o[7] = f2bf(s1.w * n1.w);
  *(uint4*)(Xbf + (size_t)idx * 8) = *(const uint4*)o;
}

// ---------------------------------------------------------------------------
// Fused layer GEMM: C_tile 128m x 128n, K=512 in 8 chunks of 64.
// Dual accumulators (H and T) share A-fragments. XOR-swizzled LDS so that
// global_load_lds staging is contiguous AND frag ds_read_b128 is conflict-free.
// __launch_bounds__(256, 2): cap unified VGPR+AGPR at 256 -> 2 waves/SIMD
// (128 acc + ~24 ptrs + ~24 frags fits) -> 2 blocks/CU for barrier overlap.
// Epilogue: highway combine, write S (fp32) + SD (bf16) or final out.
// ---------------------------------------------------------------------------
__global__ __launch_bounds__(256, 2) void layer_gemm(
    const u16* __restrict__ Abf,    // [65536][512] bf16 (X' or SD)
    const u16* __restrict__ WtH,    // [512 n][512 k] bf16
    const u16* __restrict__ WtT,
    const float* __restrict__ hbv,  // [512] H bias vec (bH or rHb[l])
    const float* __restrict__ tbv,  // [512] T bias vec
    const float* __restrict__ vH0,  // [32][512] (layer0) or null
    const float* __restrict__ vT0,
    const float* __restrict__ h0,   // [512]
    const float* __restrict__ noise_s, // [32][512]
    const float* Sprev,             // fp32, null for layer0 (may alias Snew/Out)
    float* Snew,                    // fp32 (layers 0,1)
    u16* __restrict__ SDnew,        // bf16 (layers 0,1)
    float* Out,                     // fp32 (layer2)
    int layer) {
  __shared__ u16 lds[24576];        // A:8192, BH:8192, BT:8192 (48 KiB)
  u16* ldsA  = lds;
  u16* ldsBH = lds + 8192;
  u16* ldsBT = lds + 16384;

  const int tid  = threadIdx.x;
  const int lane = tid & 63, wid = tid >> 6;
  const int bid  = blockIdx.x;
  const int m0   = (bid >> 2) * 128;
  const int c0   = (bid & 3) * 128;
  const int bidx = m0 >> 11;            // batch index (tile never crosses b)
  const int q  = lane >> 4, mr = lane & 15;
  const int wqm = wid >> 1, wqn = wid & 1;

  // Per-lane staging addresses. LDS slot s (16B) holds granule (row=s>>3,
  // k8 = (s&7) ^ (row&7)) of the current k-chunk.
  const u16* gA[4]; const u16* gBH[4]; const u16* gBT[4];
  u16* lA[4]; u16* lBH[4]; u16* lBT[4];
#pragma unroll
  for (int t = 0; t < 4; ++t) {
    int s  = wid * 256 + t * 64 + lane;
    int rm = s >> 3;
    int k8 = (s & 7) ^ (rm & 7);
    gA[t]  = Abf + (size_t)(m0 + rm) * DD + k8 * 8;
    gBH[t] = WtH + (size_t)(c0 + rm) * DD + k8 * 8;
    gBT[t] = WtT + (size_t)(c0 + rm) * DD + k8 * 8;
    int lofs = (wid * 256 + t * 64) * 8;
    lA[t] = ldsA + lofs; lBH[t] = ldsBH + lofs; lBT[t] = ldsBT + lofs;
  }

  f32x4 accH[4][4], accT[4][4];
#pragma unroll
  for (int i = 0; i < 4; ++i)
#pragma unroll
    for (int j = 0; j < 4; ++j) {
      accH[i][j] = (f32x4){0.f, 0.f, 0.f, 0.f};
      accT[i][j] = (f32x4){0.f, 0.f, 0.f, 0.f};
    }

  for (int kb = 0; kb < 8; ++kb) {
    __syncthreads();                 // prior chunk's LDS reads complete
    const int ko = kb * 64;          // k advance in elements (=128B)
#pragma unroll
    for (int t = 0; t < 4; ++t) {
      async16(gA[t] + ko,  lA[t]);
      async16(gBH[t] + ko, lBH[t]);
      async16(gBT[t] + ko, lBT[t]);
    }
    __syncthreads();                 // drains vmcnt: LDS filled

#pragma unroll
    for (int ks = 0; ks < 2; ++ks) {
      const int jj = ((((ks << 2) + q) ^ (mr & 7)) << 3); // u16 offset in row
      short8 a[4];
#pragma unroll
      for (int mt = 0; mt < 4; ++mt)
        a[mt] = *(const short8*)(ldsA + (wqm * 64 + mt * 16 + mr) * 64 + jj);
#pragma unroll
      for (int nt = 0; nt < 4; ++nt) {
        int nofs = (wqn * 64 + nt * 16 + mr) * 64 + jj;
        short8 bh = *(const short8*)(ldsBH + nofs);
        short8 bt = *(const short8*)(ldsBT + nofs);
#pragma unroll
        for (int mt = 0; mt < 4; ++mt) {
          accH[mt][nt] = __builtin_amdgcn_mfma_f32_16x16x32_bf16(a[mt], bh, accH[mt][nt], 0, 0, 0);
          accT[mt][nt] = __builtin_amdgcn_mfma_f32_16x16x32_bf16(a[mt], bt, accT[mt][nt], 0, 0, 0);
        }
      }
    }
  }

  // Epilogue. C/D layout: col = lane&15, row = (lane>>4)*4 + reg.
  const int b512 = bidx * DD;
#pragma unroll
  for (int nt = 0; nt < 4; ++nt) {
    const int gc = c0 + wqn * 64 + nt * 16 + mr;
    float hb = hbv[gc], tb = tbv[gc];
    float nsc = 0.f, h0c = 0.f;
    if (layer == 0) {
      hb += vH0[b512 + gc];
      tb += vT0[b512 + gc];
      h0c = h0[gc];
    }
    if (layer < 2) nsc = noise_s[b512 + gc];
#pragma unroll
    for (int mt = 0; mt < 4; ++mt) {
      const int gmb = m0 + wqm * 64 + mt * 16 + q * 4;
#pragma unroll
      for (int r = 0; r < 4; ++r) {
        const size_t o = (size_t)(gmb + r) * DD + gc;
        float sp = (layer == 0) ? h0c : Sprev[o];
        float hg = tanhf(accH[mt][nt][r] + hb);
        float tg = 1.f / (1.f + __expf(-(accT[mt][nt][r] + tb)));
        float sn = (hg - sp) * tg + sp;
        if (layer < 2) {
          Snew[o] = sn;
          SDnew[o] = f2bf(sn * nsc);
        } else {
          Out[o] = sn;
        }
      }
    }
  }
}

// ---------------------------------------------------------------------------
extern "C" void kernel_launch(void* const* d_in, const int* in_sizes, int n_in,
                              void* d_out, int out_size, void* d_ws, size_t ws_size,
                              hipStream_t stream) {
  const float* h0  = (const float*)d_in[0];
  const float* seq = (const float*)d_in[1];
  const float* wH  = (const float*)d_in[2];
  const float* bH  = (const float*)d_in[3];
  const float* wT  = (const float*)d_in[4];
  const float* bT  = (const float*)d_in[5];
  const float* rHw = (const float*)d_in[6];
  const float* rHb = (const float*)d_in[7];
  const float* rTw = (const float*)d_in[8];
  const float* rTb = (const float*)d_in[9];
  float* out = (float*)d_out;

  char* ws = (char*)d_ws;
  float* noise_i = (float*)(ws);                       // 64 KB
  float* noise_s = (float*)(ws + (64 << 10));          // 64 KB
  float* vH0     = (float*)(ws + (128 << 10));         // 64 KB
  float* vT0     = (float*)(ws + (192 << 10));         // 64 KB
  u16* Wt    = (u16*)(ws + (256 << 10));               // 6 x 512 KB
  u16* Xbf   = (u16*)(ws + (4ull << 20));              // 64 MB (also SD1)
  u16* SD0   = (u16*)(ws + (68ull << 20));             // 64 MB

  noise_kernel<<<64, 256, 0, stream>>>(noise_i, noise_s);
  vec0_kernel<<<64, 256, 0, stream>>>(h0, noise_s, rHw, rHb, rTw, rTb, vH0, vT0);
  wt_all<<<384, 256, 0, stream>>>(wH, wT, rHw, rTw, Wt);
  xprep<<<M_TOT * DIN / 8 / 256, 256, 0, stream>>>(seq, noise_i, Xbf);

  const int NBLK = (M_TOT / 128) * (DD / 128);   // 2048
  // Layer 0: A=Xbf, S->out, SD->SD0
  layer_gemm<<<NBLK, NTHREADS, 0, stream>>>(
      Xbf, Wt + 0 * WSZ, Wt + 1 * WSZ, bH, bT, vH0, vT0, h0, noise_s,
      nullptr, out, SD0, nullptr, 0);
  // Layer 1: A=SD0, Sprev=out, S->out (in place, disjoint per element), SD->Xbf
  layer_gemm<<<NBLK, NTHREADS, 0, stream>>>(
      SD0, Wt + 2 * WSZ, Wt + 3 * WSZ, rHb + DD, rTb + DD, nullptr, nullptr, h0, noise_s,
      out, out, Xbf, nullptr, 1);
  // Layer 2: A=Xbf(SD1), Sprev=out, final -> out
  layer_gemm<<<NBLK, NTHREADS, 0, stream>>>(
      Xbf, Wt + 4 * WSZ, Wt + 5 * WSZ, rHb + 2 * DD, rTb + 2 * DD, nullptr, nullptr, h0, noise_s,
      out, nullptr, nullptr, out, 2);
}